// Round 9
// baseline (262.029 us; speedup 1.0000x reference)
//
#include <hip/hip_runtime.h>
#include <hip/hip_bf16.h>
#include <math.h>

#define H 256
#define F 512
#define E 8
#define T_TOK 32768
#define BM 64    // tokens per block
#define FC 64    // F-chunk size
#define NCH 64   // E * F/FC chunks

typedef float    f32x4 __attribute__((__ext_vector_type__(4)));
typedef _Float16 f16x8 __attribute__((__ext_vector_type__(8)));
typedef _Float16 f16x4 __attribute__((__ext_vector_type__(4)));

// full drain + barrier (R4-proven publish)
#define BAR_ALL() asm volatile("s_waitcnt vmcnt(0) lgkmcnt(0)\ns_barrier" ::: "memory")

__device__ __forceinline__ void async_copy16(const void* g, void* l) {
    __builtin_amdgcn_global_load_lds((const __attribute__((address_space(1))) void*)g,
                                     (__attribute__((address_space(3))) void*)l, 16, 0, 0);
}

// gelu(v) = v - v * rcp(1 + exp2(v*(c1 + c2*v^2)))   [tanh-approx]
__device__ __forceinline__ float gelu_fast(float v) {
    const float c1 = 2.302117236f;
    const float c2 = 0.102943842f;
    float u2 = v * fmaf(c2, v * v, c1);
    float ex = __builtin_amdgcn_exp2f(u2);
    float r = __builtin_amdgcn_rcpf(ex + 1.0f);
    return v - v * r;
}

// W1[e][h][f] fp32 -> W1t[e][f][ h ^ ((f&7)<<3) ] fp16  (swizzle baked)
__global__ void prep_w1(const float* __restrict__ in, _Float16* __restrict__ out) {
    __shared__ float t[32][33];
    int e = blockIdx.z, f0 = blockIdx.x * 32, h0 = blockIdx.y * 32;
    int tx = threadIdx.x, ty = threadIdx.y;
    const float* ip = in + ((size_t)e * H + h0) * F + f0;
    for (int i = 0; i < 32; i += 8) t[ty + i][tx] = ip[(size_t)(ty + i) * F + tx];
    __syncthreads();
    _Float16* op = out + (size_t)e * F * H;
    for (int i = 0; i < 32; i += 8) {
        int f = f0 + ty + i, h = h0 + tx;
        op[(size_t)f * H + (h ^ ((f & 7) << 3))] = (_Float16)t[tx][ty + i];
    }
}

// W2[e][f][h] fp32 -> W2p packed MFMA A-fragments.
// chunk s=e*8+c; frag idx G = (hw*8 + i*2 + ks)*64 + lane; f16 offset = s*16384 + G*8
// value[d] = W2[e][c*64 + ks*32 + (lane>>4)*8 + d][hw*64 + i*16 + (lane&15)]
__global__ void prep_w2p(const float* __restrict__ in, _Float16* __restrict__ out) {
    __shared__ float t[64][65];   // [f_local][h_local]
    int blk = blockIdx.x;         // 256 = 64 chunks x 4 hw
    int s = blk >> 2, hw = blk & 3;
    int e = s >> 3, c = s & 7;
    int tid = threadIdx.x;        // 256
    int fl = tid >> 2, h16 = (tid & 3) * 16;
    const float* ip = in + ((size_t)(e * F + c * 64 + fl)) * H + hw * 64 + h16;
#pragma unroll
    for (int q = 0; q < 4; ++q) {
        float4 v = *(const float4*)(ip + q * 4);
        t[fl][h16 + q * 4 + 0] = v.x;
        t[fl][h16 + q * 4 + 1] = v.y;
        t[fl][h16 + q * 4 + 2] = v.z;
        t[fl][h16 + q * 4 + 3] = v.w;
    }
    __syncthreads();
#pragma unroll
    for (int r = 0; r < 2; ++r) {
        int g = tid * 2 + r;              // 0..511 within this hw
        int lane = g & 63, iks = g >> 6;  // iks = i*2 + ks
        int fb = (iks & 1) * 32 + (lane >> 4) * 8;
        int hl = (iks >> 1) * 16 + (lane & 15);
        f16x8 v;
#pragma unroll
        for (int d = 0; d < 8; ++d) v[d] = (_Float16)t[fb + d][hl];
        *(f16x8*)(out + (size_t)s * 16384 + ((size_t)hw * 512 + g) * 8) = v;
    }
}

__global__ void gate_kernel(const float* __restrict__ x, const float* __restrict__ Wg,
                            const float* __restrict__ bg, float* __restrict__ probs) {
    int gid = blockIdx.x * blockDim.x + threadIdx.x;
    int t = gid >> 3, e = gid & 7;
    const float* xr = x + (size_t)t * H;
    float acc = 0.f;
    for (int k = 0; k < H; k += 4) {
        float4 xv = *(const float4*)(xr + k);
        acc += xv.x * Wg[(k + 0) * E + e] + xv.y * Wg[(k + 1) * E + e]
             + xv.z * Wg[(k + 2) * E + e] + xv.w * Wg[(k + 3) * E + e];
    }
    acc += bg[e];
    float m = acc;
    for (int s = 1; s < 8; s <<= 1) m = fmaxf(m, __shfl_xor(m, s, 8));
    float p = expf(acc - m);
    float sum = p;
    for (int s = 1; s < 8; s <<= 1) sum += __shfl_xor(sum, s, 8);
    probs[gid] = p / sum;
}

// stage chunk s's W1 (32KB): linear async copies (swizzle baked in prep)
__device__ __forceinline__ void stage_w1(const _Float16* W1t, int s, _Float16* w1d,
                                         int wid, int lane) {
    const char* src = (const char*)W1t + (size_t)s * 32768;
#pragma unroll
    for (int q = 0; q < 4; ++q) {
        int o = (wid * 4 + q) * 1024 + lane * 16;
        async_copy16(src + o, (char*)w1d + o);
    }
}

// ---- main fused MoE FFN: BM=64, grid 512, 2 blocks/CU, conservative sync
__global__ __launch_bounds__(512, 4) void moe_main(
    const float* __restrict__ x, const _Float16* __restrict__ W1t,
    const float* __restrict__ b1, const _Float16* __restrict__ W2p,
    const float* __restrict__ b2, const float* __restrict__ probs,
    float* __restrict__ out) {

    __shared__ __align__(16) _Float16 w1s[2][FC * H];  // 2 x 32 KB
    __shared__ __align__(16) _Float16 hs[2][BM * FC];  // 2 x 8 KB  (80 KB total)

    int tid = threadIdx.x;
    int lane = tid & 63, wid = tid >> 6;
    int t0 = blockIdx.x * BM;
    int l15 = lane & 15, l4 = lane >> 4;

    int fw = wid >> 2, tw1 = wid & 3;   // GEMM1: 2(f-half 32) x 4(tok-quarter 16)
    int hw = wid >> 1, tw2 = wid & 1;   // GEMM2: 4(h 64) x 2(tok 32)

    // x B-fragments in registers: 1 token row per lane, all of H
    f16x8 xf[8];
    {
        const float* xr = x + (size_t)(t0 + tw1 * 16 + l15) * H + (l4 << 3);
#pragma unroll
        for (int ks = 0; ks < 8; ++ks) {
            float4 v0 = *(const float4*)(xr + ks * 32);
            float4 v1 = *(const float4*)(xr + ks * 32 + 4);
            f16x8 hv;
            hv[0] = (_Float16)v0.x; hv[1] = (_Float16)v0.y; hv[2] = (_Float16)v0.z; hv[3] = (_Float16)v0.w;
            hv[4] = (_Float16)v1.x; hv[5] = (_Float16)v1.y; hv[6] = (_Float16)v1.z; hv[7] = (_Float16)v1.w;
            xf[ks] = hv;
        }
    }
    // gate probs for this wave's GEMM1 token row, all experts
    float pg[8];
    {
        const float* pp = probs + (size_t)(t0 + tw1 * 16 + l15) * E;
        float4 p0 = *(const float4*)pp, p1 = *(const float4*)(pp + 4);
        pg[0] = p0.x; pg[1] = p0.y; pg[2] = p0.z; pg[3] = p0.w;
        pg[4] = p1.x; pg[5] = p1.y; pg[6] = p1.z; pg[7] = p1.w;
    }

    stage_w1(W1t, 0, w1s[0], wid, lane);
    BAR_ALL();

    f32x4 yacc[4][2];
#pragma unroll
    for (int i = 0; i < 4; ++i)
#pragma unroll
        for (int j = 0; j < 2; ++j) yacc[i][j] = (f32x4){0.f, 0.f, 0.f, 0.f};

    for (int s = 0; s < NCH; ++s) {
        int b = s & 1;
        int e = s >> 3, c = s & 7, fbase = c * FC;
        const _Float16* w1p = w1s[b];

        // (1) av: packed W2 fragments for THIS chunk (coalesced, L2-hot)
        f16x8 av[4][2];
        {
            const _Float16* wb = W2p + (size_t)s * 16384 + ((size_t)(hw * 8) * 64 + lane) * 8;
#pragma unroll
            for (int i = 0; i < 4; ++i) {
                av[i][0] = *(const f16x8*)(wb + (i * 2 + 0) * 512);
                av[i][1] = *(const f16x8*)(wb + (i * 2 + 1) * 512);
            }
        }
        // b1 fragments
        float4 bvq[2];
#pragma unroll
        for (int i = 0; i < 2; ++i)
            bvq[i] = *(const float4*)(b1 + (size_t)e * F + fbase + (fw * 2 + i) * 16 + l4 * 4);

        // (2) prefetch next W1 chunk (drained at the mid barrier)
        if (s + 1 < NCH)
            stage_w1(W1t, s + 1, w1s[b ^ 1], wid, lane);

        // (3) GEMM1: hT[f][tok], K=H (A from w1s, B = xf regs)
        f32x4 hacc[2];
        hacc[0] = hacc[1] = (f32x4){0.f, 0.f, 0.f, 0.f};
#pragma unroll
        for (int ks = 0; ks < 8; ++ks) {
            int kidx = ks * 32 + (l4 << 3);
            int fr0 = fw * 32 + l15, fr1 = fr0 + 16;
            f16x8 a0 = *(const f16x8*)&w1p[fr0 * H + (kidx ^ ((fr0 & 7) << 3))];
            f16x8 a1 = *(const f16x8*)&w1p[fr1 * H + (kidx ^ ((fr1 & 7) << 3))];
            hacc[0] = __builtin_amdgcn_mfma_f32_16x16x32_f16(a0, xf[ks], hacc[0], 0, 0, 0);
            hacc[1] = __builtin_amdgcn_mfma_f32_16x16x32_f16(a1, xf[ks], hacc[1], 0, 0, 0);
        }

        // (4) GELU + gate-fold -> hs[b]
        float p = pg[e];
#pragma unroll
        for (int i = 0; i < 2; ++i) {
            int flocal = (fw * 2 + i) * 16 + l4 * 4;
            float4 bv = bvq[i];
            int tokl = tw1 * 16 + l15;
            f16x4 hp;
            hp[0] = (_Float16)(p * gelu_fast(hacc[i][0] + bv.x));
            hp[1] = (_Float16)(p * gelu_fast(hacc[i][1] + bv.y));
            hp[2] = (_Float16)(p * gelu_fast(hacc[i][2] + bv.z));
            hp[3] = (_Float16)(p * gelu_fast(hacc[i][3] + bv.w));
            int idx = (tokl * FC + flocal) ^ ((tokl & 7) << 3);
            *(f16x4*)&hs[b][idx] = hp;
        }
        BAR_ALL();  // hs[b] visible + next W1 chunk landed (full drain, R4-proven)

        // (5) GEMM2: y[h][tok] += W2chunk . hs^T, K=FC (av in regs)
#pragma unroll
        for (int ks = 0; ks < FC / 32; ++ks) {
            int kidx = ks * 32 + (l4 << 3);
            f16x8 bv2[2];
#pragma unroll
            for (int j = 0; j < 2; ++j) {
                int tok = tw2 * 32 + j * 16 + l15;
                bv2[j] = *(const f16x8*)&hs[b][(tok * FC + kidx) ^ ((tok & 7) << 3)];
            }
#pragma unroll
            for (int i = 0; i < 4; ++i)
#pragma unroll
                for (int j = 0; j < 2; ++j)
                    yacc[i][j] = __builtin_amdgcn_mfma_f32_16x16x32_f16(av[i][ks], bv2[j], yacc[i][j], 0, 0, 0);
        }
        BAR_ALL();  // hs[b] reads retired before next iteration's writes
    }

    // epilogue: out = yacc + sum_e p_e * b2_e
#pragma unroll
    for (int j = 0; j < 2; ++j) {
        int tok = t0 + tw2 * 32 + j * 16 + l15;
        float pe[8];
#pragma unroll
        for (int e = 0; e < 8; ++e) pe[e] = probs[(size_t)tok * E + e];
#pragma unroll
        for (int i = 0; i < 4; ++i) {
            int h0 = hw * 64 + i * 16 + l4 * 4;
            f32x4 acc = yacc[i][j];
#pragma unroll
            for (int e = 0; e < 8; ++e) {
                float4 b2v = *(const float4*)(b2 + (size_t)e * H + h0);
                acc[0] += pe[e] * b2v.x;
                acc[1] += pe[e] * b2v.y;
                acc[2] += pe[e] * b2v.z;
                acc[3] += pe[e] * b2v.w;
            }
            *(f32x4*)(out + (size_t)tok * H + h0) = acc;
        }
    }
}

extern "C" void kernel_launch(void* const* d_in, const int* in_sizes, int n_in,
                              void* d_out, int out_size, void* d_ws, size_t ws_size,
                              hipStream_t stream) {
    const float* x  = (const float*)d_in[0];
    const float* Wg = (const float*)d_in[1];
    const float* bg = (const float*)d_in[2];
    const float* W1 = (const float*)d_in[3];
    const float* b1 = (const float*)d_in[4];
    const float* W2 = (const float*)d_in[5];
    const float* b2 = (const float*)d_in[6];
    float* out = (float*)d_out;

    _Float16* W1t = (_Float16*)d_ws;                       // [E][F][H] fp16 swizzled, 2 MB
    _Float16* W2p = W1t + (size_t)E * F * H;               // packed fragments, 2 MB
    float* probs  = (float*)(W2p + (size_t)64 * 16384);    // [T][E] fp32, 1 MB

    dim3 tb(32, 8);
    prep_w1<<<dim3(F / 32, H / 32, E), tb, 0, stream>>>(W1, W1t);
    prep_w2p<<<256, 256, 0, stream>>>(W2, W2p);
    gate_kernel<<<(T_TOK * E) / 256, 256, 0, stream>>>(x, Wg, bg, probs);
    moe_main<<<T_TOK / BM, 512, 0, stream>>>(x, W1t, b1, W2p, b2, probs, out);
}

// Round 10
// 243.064 us; speedup vs baseline: 1.0780x; 1.0780x over previous
//
#include <hip/hip_runtime.h>
#include <hip/hip_bf16.h>
#include <math.h>

#define H 256
#define F 512
#define E 8
#define T_TOK 32768
#define BM 128   // tokens per block
#define FC 64    // F-chunk size
#define NCH 64   // E * F/FC chunks

typedef float    f32x4 __attribute__((__ext_vector_type__(4)));
typedef _Float16 f16x8 __attribute__((__ext_vector_type__(8)));
typedef _Float16 f16x4 __attribute__((__ext_vector_type__(4)));

// full drain + barrier (R4-proven publish; the ONLY sync primitive used)
#define BAR_ALL() asm volatile("s_waitcnt vmcnt(0) lgkmcnt(0)\ns_barrier" ::: "memory")

__device__ __forceinline__ void async_copy16(const void* g, void* l) {
    __builtin_amdgcn_global_load_lds((const __attribute__((address_space(1))) void*)g,
                                     (__attribute__((address_space(3))) void*)l, 16, 0, 0);
}

// gelu(v) = v - v * rcp(1 + exp2(v*(c1 + c2*v^2)))   [tanh-approx]
__device__ __forceinline__ float gelu_fast(float v) {
    const float c1 = 2.302117236f;
    const float c2 = 0.102943842f;
    float u2 = v * fmaf(c2, v * v, c1);
    float ex = __builtin_amdgcn_exp2f(u2);
    float r = __builtin_amdgcn_rcpf(ex + 1.0f);
    return v - v * r;
}

// W1[e][h][f] fp32 -> W1t[e][f][ h ^ ((f&7)<<3) ] fp16  (swizzle baked)
__global__ void prep_w1(const float* __restrict__ in, _Float16* __restrict__ out) {
    __shared__ float t[32][33];
    int e = blockIdx.z, f0 = blockIdx.x * 32, h0 = blockIdx.y * 32;
    int tx = threadIdx.x, ty = threadIdx.y;
    const float* ip = in + ((size_t)e * H + h0) * F + f0;
    for (int i = 0; i < 32; i += 8) t[ty + i][tx] = ip[(size_t)(ty + i) * F + tx];
    __syncthreads();
    _Float16* op = out + (size_t)e * F * H;
    for (int i = 0; i < 32; i += 8) {
        int f = f0 + ty + i, h = h0 + tx;
        op[(size_t)f * H + (h ^ ((f & 7) << 3))] = (_Float16)t[tx][ty + i];
    }
}

// W2[e][f][h] fp32 -> W2p packed MFMA A-fragments for the 8x2 wave grid.
// chunk s=e*8+c; ht = h>>4 (0..15); G = (ht*2 + ks)*64 + lane
// value[d] = W2[e][c*64 + ks*32 + (lane>>4)*8 + d][ht*16 + (lane&15)]
__global__ void prep_w2p(const float* __restrict__ in, _Float16* __restrict__ out) {
    __shared__ float t[64][65];   // [f_local][h_local]
    int blk = blockIdx.x;         // 256 = 64 chunks x 4 h-quarters
    int s = blk >> 2, q = blk & 3;
    int e = s >> 3, c = s & 7;
    int tid = threadIdx.x;        // 256
    int fl = tid >> 2, h16 = (tid & 3) * 16;
    const float* ip = in + ((size_t)(e * F + c * 64 + fl)) * H + q * 64 + h16;
#pragma unroll
    for (int w = 0; w < 4; ++w) {
        float4 v = *(const float4*)(ip + w * 4);
        t[fl][h16 + w * 4 + 0] = v.x;
        t[fl][h16 + w * 4 + 1] = v.y;
        t[fl][h16 + w * 4 + 2] = v.z;
        t[fl][h16 + w * 4 + 3] = v.w;
    }
    __syncthreads();
#pragma unroll
    for (int r = 0; r < 2; ++r) {
        int g2 = tid * 2 + r;               // 0..511 within this quarter
        int htl = g2 >> 7;                  // 0..3 local h-tile
        int rem = g2 & 127;
        int ks = rem >> 6, lane = rem & 63;
        int fb = ks * 32 + (lane >> 4) * 8;
        int hl = htl * 16 + (lane & 15);
        f16x8 v;
#pragma unroll
        for (int d = 0; d < 8; ++d) v[d] = (_Float16)t[fb + d][hl];
        int G = ((q * 4 + htl) * 2 + ks) * 64 + lane;
        *(f16x8*)(out + (size_t)s * 16384 + (size_t)G * 8) = v;
    }
}

__global__ void gate_kernel(const float* __restrict__ x, const float* __restrict__ Wg,
                            const float* __restrict__ bg, float* __restrict__ probs) {
    int gid = blockIdx.x * blockDim.x + threadIdx.x;
    int t = gid >> 3, e = gid & 7;
    const float* xr = x + (size_t)t * H;
    float acc = 0.f;
    for (int k = 0; k < H; k += 4) {
        float4 xv = *(const float4*)(xr + k);
        acc += xv.x * Wg[(k + 0) * E + e] + xv.y * Wg[(k + 1) * E + e]
             + xv.z * Wg[(k + 2) * E + e] + xv.w * Wg[(k + 3) * E + e];
    }
    acc += bg[e];
    float m = acc;
    for (int s = 1; s < 8; s <<= 1) m = fmaxf(m, __shfl_xor(m, s, 8));
    float p = expf(acc - m);
    float sum = p;
    for (int s = 1; s < 8; s <<= 1) sum += __shfl_xor(sum, s, 8);
    probs[gid] = p / sum;
}

// stage chunk s's W1 (32KB): linear async copies; 16 waves x 2 segs
__device__ __forceinline__ void stage_w1(const _Float16* W1t, int s, _Float16* w1d,
                                         int wid, int lane) {
    const char* src = (const char*)W1t + (size_t)s * 32768;
#pragma unroll
    for (int q = 0; q < 2; ++q) {
        int o = (wid * 2 + q) * 1024 + lane * 16;
        async_copy16(src + o, (char*)w1d + o);
    }
}

// ---- main fused MoE FFN: BM=128, 1024 threads (16 waves), 1 barrier/chunk
__global__ __launch_bounds__(1024, 4) void moe_main(
    const float* __restrict__ x, const _Float16* __restrict__ W1t,
    const float* __restrict__ b1, const _Float16* __restrict__ W2p,
    const float* __restrict__ b2, const float* __restrict__ probs,
    float* __restrict__ out) {

    __shared__ __align__(16) _Float16 w1s[2][FC * H];  // 2 x 32 KB
    __shared__ __align__(16) _Float16 hs[2][BM * FC];  // 2 x 16 KB  (96 KB total)

    int tid = threadIdx.x;
    int lane = tid & 63, wid = tid >> 6;
    int t0 = blockIdx.x * BM;
    int l15 = lane & 15, l4 = lane >> 4;

    int fw = wid >> 3, tw1 = wid & 7;   // GEMM1: 2(f-half 32) x 8(tok-16)
    int hw = wid >> 1, tw2 = wid & 1;   // GEMM2: 8(h-32) x 2(tok-64)

    // x B-fragments in registers: 1 token row per lane, all of H (32 VGPR)
    f16x8 xf[8];
    {
        const float* xr = x + (size_t)(t0 + tw1 * 16 + l15) * H + (l4 << 3);
#pragma unroll
        for (int ks = 0; ks < 8; ++ks) {
            float4 v0 = *(const float4*)(xr + ks * 32);
            float4 v1 = *(const float4*)(xr + ks * 32 + 4);
            f16x8 hv;
            hv[0] = (_Float16)v0.x; hv[1] = (_Float16)v0.y; hv[2] = (_Float16)v0.z; hv[3] = (_Float16)v0.w;
            hv[4] = (_Float16)v1.x; hv[5] = (_Float16)v1.y; hv[6] = (_Float16)v1.z; hv[7] = (_Float16)v1.w;
            xf[ks] = hv;
        }
    }
    // gate probs for this wave's GEMM1 token row, all experts
    float pg[8];
    {
        const float* pp = probs + (size_t)(t0 + tw1 * 16 + l15) * E;
        float4 p0 = *(const float4*)pp, p1 = *(const float4*)(pp + 4);
        pg[0] = p0.x; pg[1] = p0.y; pg[2] = p0.z; pg[3] = p0.w;
        pg[4] = p1.x; pg[5] = p1.y; pg[6] = p1.z; pg[7] = p1.w;
    }

    stage_w1(W1t, 0, w1s[0], wid, lane);
    BAR_ALL();

    f32x4 yacc[2][4];
#pragma unroll
    for (int i = 0; i < 2; ++i)
#pragma unroll
        for (int j = 0; j < 4; ++j) yacc[i][j] = (f32x4){0.f, 0.f, 0.f, 0.f};

    f16x8 av[2][2];   // GEMM2 A-fragments for chunk r, loaded in region r, used in r+1

    for (int s = 0; s < NCH; ++s) {
        int b = s & 1;
        int e = s >> 3, c = s & 7, fbase = c * FC;
        const _Float16* w1p = w1s[b];

        // (1) issue DMA for chunk s+1 (covered by this whole region, drained at BAR)
        if (s + 1 < NCH)
            stage_w1(W1t, s + 1, w1s[b ^ 1], wid, lane);

        // (2) GEMM2 for chunk s-1: av in regs, hs[b^1] (written 2 regions ago, safe)
        if (s > 0) {
#pragma unroll
            for (int ks = 0; ks < 2; ++ks) {
                int kidx = ks * 32 + (l4 << 3);
                f16x8 bv2[4];
#pragma unroll
                for (int j = 0; j < 4; ++j) {
                    int tok = tw2 * 64 + j * 16 + l15;
                    bv2[j] = *(const f16x8*)&hs[b ^ 1][(tok * FC + kidx) ^ ((tok & 7) << 3)];
                }
#pragma unroll
                for (int i = 0; i < 2; ++i)
#pragma unroll
                    for (int j = 0; j < 4; ++j)
                        yacc[i][j] = __builtin_amdgcn_mfma_f32_16x16x32_f16(av[i][ks], bv2[j], yacc[i][j], 0, 0, 0);
            }
        }

        // (3) issue av loads for THIS chunk (cover = GEMM1+GELU below) + b1 frags
        {
            const _Float16* wb = W2p + (size_t)s * 16384 + (size_t)lane * 8;
#pragma unroll
            for (int i = 0; i < 2; ++i)
#pragma unroll
                for (int ks = 0; ks < 2; ++ks)
                    av[i][ks] = *(const f16x8*)(wb + (((hw * 2 + i) * 2 + ks) * 64) * 8);
        }
        float4 bvq[2];
#pragma unroll
        for (int i = 0; i < 2; ++i)
            bvq[i] = *(const float4*)(b1 + (size_t)e * F + fbase + (fw * 2 + i) * 16 + l4 * 4);

        // (4) GEMM1 chunk s: A from w1s[b], B = xf regs
        f32x4 hacc[2];
        hacc[0] = hacc[1] = (f32x4){0.f, 0.f, 0.f, 0.f};
#pragma unroll
        for (int ks = 0; ks < 8; ++ks) {
            int kidx = ks * 32 + (l4 << 3);
            int fr0 = fw * 32 + l15, fr1 = fr0 + 16;
            f16x8 a0 = *(const f16x8*)&w1p[fr0 * H + (kidx ^ ((fr0 & 7) << 3))];
            f16x8 a1 = *(const f16x8*)&w1p[fr1 * H + (kidx ^ ((fr1 & 7) << 3))];
            hacc[0] = __builtin_amdgcn_mfma_f32_16x16x32_f16(a0, xf[ks], hacc[0], 0, 0, 0);
            hacc[1] = __builtin_amdgcn_mfma_f32_16x16x32_f16(a1, xf[ks], hacc[1], 0, 0, 0);
        }

        // (5) GELU + gate-fold -> hs[b]
        float p = pg[e];
#pragma unroll
        for (int i = 0; i < 2; ++i) {
            int flocal = (fw * 2 + i) * 16 + l4 * 4;
            float4 bv = bvq[i];
            int tokl = tw1 * 16 + l15;
            f16x4 hp;
            hp[0] = (_Float16)(p * gelu_fast(hacc[i][0] + bv.x));
            hp[1] = (_Float16)(p * gelu_fast(hacc[i][1] + bv.y));
            hp[2] = (_Float16)(p * gelu_fast(hacc[i][2] + bv.z));
            hp[3] = (_Float16)(p * gelu_fast(hacc[i][3] + bv.w));
            int idx = (tokl * FC + flocal) ^ ((tokl & 7) << 3);
            *(f16x4*)&hs[b][idx] = hp;
        }

        // (6) the ONE barrier: hs[b] + w1s[b^1] (DMA) published, all reads retired
        BAR_ALL();
    }

    // final GEMM2 for chunk NCH-1 (hs[1], av from last region)
    {
        int b = (NCH - 1) & 1;
#pragma unroll
        for (int ks = 0; ks < 2; ++ks) {
            int kidx = ks * 32 + (l4 << 3);
            f16x8 bv2[4];
#pragma unroll
            for (int j = 0; j < 4; ++j) {
                int tok = tw2 * 64 + j * 16 + l15;
                bv2[j] = *(const f16x8*)&hs[b][(tok * FC + kidx) ^ ((tok & 7) << 3)];
            }
#pragma unroll
            for (int i = 0; i < 2; ++i)
#pragma unroll
                for (int j = 0; j < 4; ++j)
                    yacc[i][j] = __builtin_amdgcn_mfma_f32_16x16x32_f16(av[i][ks], bv2[j], yacc[i][j], 0, 0, 0);
        }
    }

    // epilogue: out = yacc + sum_e p_e * b2_e
#pragma unroll
    for (int j = 0; j < 4; ++j) {
        int tok = t0 + tw2 * 64 + j * 16 + l15;
        float pe[8];
#pragma unroll
        for (int e = 0; e < 8; ++e) pe[e] = probs[(size_t)tok * E + e];
#pragma unroll
        for (int i = 0; i < 2; ++i) {
            int h0 = hw * 32 + i * 16 + l4 * 4;
            f32x4 acc = yacc[i][j];
#pragma unroll
            for (int e = 0; e < 8; ++e) {
                float4 b2v = *(const float4*)(b2 + (size_t)e * H + h0);
                acc[0] += pe[e] * b2v.x;
                acc[1] += pe[e] * b2v.y;
                acc[2] += pe[e] * b2v.z;
                acc[3] += pe[e] * b2v.w;
            }
            *(f32x4*)(out + (size_t)tok * H + h0) = acc;
        }
    }
}

extern "C" void kernel_launch(void* const* d_in, const int* in_sizes, int n_in,
                              void* d_out, int out_size, void* d_ws, size_t ws_size,
                              hipStream_t stream) {
    const float* x  = (const float*)d_in[0];
    const float* Wg = (const float*)d_in[1];
    const float* bg = (const float*)d_in[2];
    const float* W1 = (const float*)d_in[3];
    const float* b1 = (const float*)d_in[4];
    const float* W2 = (const float*)d_in[5];
    const float* b2 = (const float*)d_in[6];
    float* out = (float*)d_out;

    _Float16* W1t = (_Float16*)d_ws;                       // [E][F][H] fp16 swizzled, 2 MB
    _Float16* W2p = W1t + (size_t)E * F * H;               // packed fragments, 2 MB
    float* probs  = (float*)(W2p + (size_t)64 * 16384);    // [T][E] fp32, 1 MB

    dim3 tb(32, 8);
    prep_w1<<<dim3(F / 32, H / 32, E), tb, 0, stream>>>(W1, W1t);
    prep_w2p<<<256, 256, 0, stream>>>(W2, W2p);
    gate_kernel<<<(T_TOK * E) / 256, 256, 0, stream>>>(x, Wg, bg, probs);
    moe_main<<<T_TOK / BM, 1024, 0, stream>>>(x, W1t, b1, W2p, b2, probs, out);
}

// Round 11
// 218.210 us; speedup vs baseline: 1.2008x; 1.1139x over previous
//
#include <hip/hip_runtime.h>
#include <hip/hip_bf16.h>
#include <math.h>

#define H 256
#define F 512
#define E 8
#define T_TOK 32768
#define BM 128   // tokens per block
#define FC 64    // F-chunk size
#define NCH 64   // E * F/FC chunks

typedef float    f32x4 __attribute__((__ext_vector_type__(4)));
typedef _Float16 f16x8 __attribute__((__ext_vector_type__(8)));
typedef _Float16 f16x4 __attribute__((__ext_vector_type__(4)));

// lgkm-only barrier: publishes LDS (hs); register global loads stay in flight
#define BAR_LG() asm volatile("s_waitcnt lgkmcnt(0)\ns_barrier" ::: "memory")

// gelu(v) = v - v * rcp(1 + exp2(v*(c1 + c2*v^2)))   [tanh-approx]
__device__ __forceinline__ float gelu_fast(float v) {
    const float c1 = 2.302117236f;
    const float c2 = 0.102943842f;
    float u2 = v * fmaf(c2, v * v, c1);
    float ex = __builtin_amdgcn_exp2f(u2);
    float r = __builtin_amdgcn_rcpf(ex + 1.0f);
    return v - v * r;
}

// W1[e][h][f] fp32 -> W1p packed GEMM1 A-fragments.
// block blk = s*2 + fw  (s = e*8+c). frag g = ks*128 + pair*64 + lane.
// value[d] = W1[e][ks*32 + (lane>>4)*8 + d][c*64 + fw*32 + pair*16 + (lane&15)]
__global__ void prep_w1p(const float* __restrict__ in, _Float16* __restrict__ out) {
    __shared__ float t[256][33];   // [h][f_local 32]
    int blk = blockIdx.x;          // 128
    int s = blk >> 1, fw = blk & 1;
    int e = s >> 3, c = s & 7;
    int f0 = c * 64 + fw * 32;
    int tid = threadIdx.x;         // 256
    int hr = tid >> 3, q = tid & 7;
#pragma unroll
    for (int pp = 0; pp < 8; ++pp) {
        int h = pp * 32 + hr;
        float4 v = *(const float4*)(in + ((size_t)e * H + h) * F + f0 + q * 4);
        t[h][q * 4 + 0] = v.x;
        t[h][q * 4 + 1] = v.y;
        t[h][q * 4 + 2] = v.z;
        t[h][q * 4 + 3] = v.w;
    }
    __syncthreads();
#pragma unroll
    for (int r = 0; r < 4; ++r) {
        int g = r * 256 + tid;             // 0..1023
        int ks = g >> 7, pair = (g >> 6) & 1, ln = g & 63;
        int l4v = ln >> 4, l15v = ln & 15;
        f16x8 v;
#pragma unroll
        for (int d = 0; d < 8; ++d) v[d] = (_Float16)t[ks * 32 + l4v * 8 + d][pair * 16 + l15v];
        *(f16x8*)(out + ((size_t)blk * 1024 + g) * 8) = v;
    }
}

// W2[e][f][h] fp32 -> W2p packed GEMM2 A-fragments (R9-proven, 4-hw wave grid).
// chunk s=e*8+c; G = (hw*8 + i*2 + ks)*64 + lane
// value[d] = W2[e][c*64 + ks*32 + (lane>>4)*8 + d][hw*64 + i*16 + (lane&15)]
__global__ void prep_w2p(const float* __restrict__ in, _Float16* __restrict__ out) {
    __shared__ float t[64][65];   // [f_local][h_local]
    int blk = blockIdx.x;         // 256 = 64 chunks x 4 hw
    int s = blk >> 2, hw = blk & 3;
    int e = s >> 3, c = s & 7;
    int tid = threadIdx.x;        // 256
    int fl = tid >> 2, h16 = (tid & 3) * 16;
    const float* ip = in + ((size_t)(e * F + c * 64 + fl)) * H + hw * 64 + h16;
#pragma unroll
    for (int q = 0; q < 4; ++q) {
        float4 v = *(const float4*)(ip + q * 4);
        t[fl][h16 + q * 4 + 0] = v.x;
        t[fl][h16 + q * 4 + 1] = v.y;
        t[fl][h16 + q * 4 + 2] = v.z;
        t[fl][h16 + q * 4 + 3] = v.w;
    }
    __syncthreads();
#pragma unroll
    for (int r = 0; r < 2; ++r) {
        int g = tid * 2 + r;              // 0..511 within this hw
        int lane = g & 63, iks = g >> 6;  // iks = i*2 + ks
        int fb = (iks & 1) * 32 + (lane >> 4) * 8;
        int hl = (iks >> 1) * 16 + (lane & 15);
        f16x8 v;
#pragma unroll
        for (int d = 0; d < 8; ++d) v[d] = (_Float16)t[fb + d][hl];
        *(f16x8*)(out + (size_t)s * 16384 + ((size_t)hw * 512 + g) * 8) = v;
    }
}

__global__ void gate_kernel(const float* __restrict__ x, const float* __restrict__ Wg,
                            const float* __restrict__ bg, float* __restrict__ probs) {
    int gid = blockIdx.x * blockDim.x + threadIdx.x;
    int t = gid >> 3, e = gid & 7;
    const float* xr = x + (size_t)t * H;
    float acc = 0.f;
    for (int k = 0; k < H; k += 4) {
        float4 xv = *(const float4*)(xr + k);
        acc += xv.x * Wg[(k + 0) * E + e] + xv.y * Wg[(k + 1) * E + e]
             + xv.z * Wg[(k + 2) * E + e] + xv.w * Wg[(k + 3) * E + e];
    }
    acc += bg[e];
    float m = acc;
    for (int s = 1; s < 8; s <<= 1) m = fmaxf(m, __shfl_xor(m, s, 8));
    float p = expf(acc - m);
    float sum = p;
    for (int s = 1; s < 8; s <<= 1) sum += __shfl_xor(sum, s, 8);
    probs[gid] = p / sum;
}

// ---- main fused MoE FFN: 8 waves, LDS = hs only, all weights reg-loaded from L2
__global__ __launch_bounds__(512, 2) void moe_main(
    const float* __restrict__ x, const _Float16* __restrict__ W1p,
    const float* __restrict__ b1, const _Float16* __restrict__ W2p,
    const float* __restrict__ b2, const float* __restrict__ probs,
    float* __restrict__ out) {

    __shared__ __align__(16) _Float16 hs[2][BM * FC];  // 2 x 16 KB (32 KB total)

    int tid = threadIdx.x;
    int lane = tid & 63, wid = tid >> 6;
    int t0 = blockIdx.x * BM;
    int l15 = lane & 15, l4 = lane >> 4;

    int fw = wid >> 2, tw1 = wid & 3;   // GEMM1: 2(f-32) x 4(tok-32)
    int hw = wid >> 1, tw2 = wid & 1;   // GEMM2: 4(h-64) x 2(tok-64)

    // x B-fragments in registers (static, 64 VGPR)
    f16x8 xf[8][2];
#pragma unroll
    for (int j = 0; j < 2; ++j) {
        const float* xr = x + (size_t)(t0 + tw1 * 32 + j * 16 + l15) * H + (l4 << 3);
#pragma unroll
        for (int ks = 0; ks < 8; ++ks) {
            float4 v0 = *(const float4*)(xr + ks * 32);
            float4 v1 = *(const float4*)(xr + ks * 32 + 4);
            f16x8 hv;
            hv[0] = (_Float16)v0.x; hv[1] = (_Float16)v0.y; hv[2] = (_Float16)v0.z; hv[3] = (_Float16)v0.w;
            hv[4] = (_Float16)v1.x; hv[5] = (_Float16)v1.y; hv[6] = (_Float16)v1.z; hv[7] = (_Float16)v1.w;
            xf[ks][j] = hv;
        }
    }

    f32x4 yacc[4][4];
#pragma unroll
    for (int i = 0; i < 4; ++i)
#pragma unroll
        for (int j = 0; j < 4; ++j) yacc[i][j] = (f32x4){0.f, 0.f, 0.f, 0.f};

    float p0g = 0.f, p1g = 0.f;

    for (int s = 0; s < NCH; ++s) {
        int b = s & 1;
        int e = s >> 3, c = s & 7, fbase = c * FC;

        if ((s & 7) == 0) {  // new expert: reload gate probs for this wave's tok rows
            p0g = probs[(size_t)(t0 + tw1 * 32 + l15) * E + e];
            p1g = probs[(size_t)(t0 + tw1 * 32 + 16 + l15) * E + e];
        }

        const _Float16* w1b = W1p + ((size_t)(s * 2 + fw) * 1024 + lane) * 8;

        // (1) W1 fragment batch 1 (ks 0..3) + av (GEMM2 A) + b1 — all L2/L1-hot
        f16x8 w1a[4][2];
#pragma unroll
        for (int ks = 0; ks < 4; ++ks) {
            w1a[ks][0] = *(const f16x8*)(w1b + (ks * 2 + 0) * 512);
            w1a[ks][1] = *(const f16x8*)(w1b + (ks * 2 + 1) * 512);
        }
        f16x8 av[4][2];
        {
            const _Float16* wb = W2p + (size_t)s * 16384 + ((size_t)(hw * 8) * 64 + lane) * 8;
#pragma unroll
            for (int i = 0; i < 4; ++i) {
                av[i][0] = *(const f16x8*)(wb + (i * 2 + 0) * 512);
                av[i][1] = *(const f16x8*)(wb + (i * 2 + 1) * 512);
            }
        }
        float4 bvq[2];
#pragma unroll
        for (int i = 0; i < 2; ++i)
            bvq[i] = *(const float4*)(b1 + (size_t)e * F + fbase + (fw * 2 + i) * 16 + l4 * 4);

        // (2) GEMM1 part 1 (ks 0..3), then stream batch 2 (ks 4..7), part 2
        f32x4 hacc[2][2];
        hacc[0][0] = hacc[0][1] = hacc[1][0] = hacc[1][1] = (f32x4){0.f, 0.f, 0.f, 0.f};
#pragma unroll
        for (int ks = 0; ks < 4; ++ks) {
            hacc[0][0] = __builtin_amdgcn_mfma_f32_16x16x32_f16(w1a[ks][0], xf[ks][0], hacc[0][0], 0, 0, 0);
            hacc[0][1] = __builtin_amdgcn_mfma_f32_16x16x32_f16(w1a[ks][0], xf[ks][1], hacc[0][1], 0, 0, 0);
            hacc[1][0] = __builtin_amdgcn_mfma_f32_16x16x32_f16(w1a[ks][1], xf[ks][0], hacc[1][0], 0, 0, 0);
            hacc[1][1] = __builtin_amdgcn_mfma_f32_16x16x32_f16(w1a[ks][1], xf[ks][1], hacc[1][1], 0, 0, 0);
        }
#pragma unroll
        for (int ks = 0; ks < 4; ++ks) {
            w1a[ks][0] = *(const f16x8*)(w1b + ((ks + 4) * 2 + 0) * 512);
            w1a[ks][1] = *(const f16x8*)(w1b + ((ks + 4) * 2 + 1) * 512);
        }
#pragma unroll
        for (int ks = 0; ks < 4; ++ks) {
            hacc[0][0] = __builtin_amdgcn_mfma_f32_16x16x32_f16(w1a[ks][0], xf[ks + 4][0], hacc[0][0], 0, 0, 0);
            hacc[0][1] = __builtin_amdgcn_mfma_f32_16x16x32_f16(w1a[ks][0], xf[ks + 4][1], hacc[0][1], 0, 0, 0);
            hacc[1][0] = __builtin_amdgcn_mfma_f32_16x16x32_f16(w1a[ks][1], xf[ks + 4][0], hacc[1][0], 0, 0, 0);
            hacc[1][1] = __builtin_amdgcn_mfma_f32_16x16x32_f16(w1a[ks][1], xf[ks + 4][1], hacc[1][1], 0, 0, 0);
        }

        // (3) GELU + gate-fold -> hs[b]
#pragma unroll
        for (int i = 0; i < 2; ++i) {
            int flocal = (fw * 2 + i) * 16 + l4 * 4;
            float4 bv = bvq[i];
#pragma unroll
            for (int j = 0; j < 2; ++j) {
                int tokl = tw1 * 32 + j * 16 + l15;
                float p = j ? p1g : p0g;
                f32x4 hv = hacc[i][j];
                f16x4 hp;
                hp[0] = (_Float16)(p * gelu_fast(hv[0] + bv.x));
                hp[1] = (_Float16)(p * gelu_fast(hv[1] + bv.y));
                hp[2] = (_Float16)(p * gelu_fast(hv[2] + bv.z));
                hp[3] = (_Float16)(p * gelu_fast(hv[3] + bv.w));
                int idx = (tokl * FC + flocal) ^ ((tokl & 7) << 3);
                *(f16x4*)&hs[b][idx] = hp;
            }
        }

        // (4) the one barrier: hs[b] published (lgkm only; reg loads stay in flight)
        BAR_LG();

        // (5) GEMM2: y += W2chunk . hs[b]^T, K=FC (av in regs)
#pragma unroll
        for (int ks = 0; ks < FC / 32; ++ks) {
            int kidx = ks * 32 + (l4 << 3);
            f16x8 bv2[4];
#pragma unroll
            for (int j = 0; j < 4; ++j) {
                int tok = tw2 * 64 + j * 16 + l15;
                bv2[j] = *(const f16x8*)&hs[b][(tok * FC + kidx) ^ ((tok & 7) << 3)];
            }
#pragma unroll
            for (int i = 0; i < 4; ++i)
#pragma unroll
                for (int j = 0; j < 4; ++j)
                    yacc[i][j] = __builtin_amdgcn_mfma_f32_16x16x32_f16(av[i][ks], bv2[j], yacc[i][j], 0, 0, 0);
        }
        // next region writes hs[b^1]; hs[b] next written at s+2, after BAR(s+1) — safe
    }

    // epilogue: out = yacc + sum_e p_e * b2_e
#pragma unroll
    for (int j = 0; j < 4; ++j) {
        int tok = t0 + tw2 * 64 + j * 16 + l15;
        float pe[8];
#pragma unroll
        for (int e = 0; e < 8; ++e) pe[e] = probs[(size_t)tok * E + e];
#pragma unroll
        for (int i = 0; i < 4; ++i) {
            int h0 = hw * 64 + i * 16 + l4 * 4;
            f32x4 acc = yacc[i][j];
#pragma unroll
            for (int e = 0; e < 8; ++e) {
                float4 b2v = *(const float4*)(b2 + (size_t)e * H + h0);
                acc[0] += pe[e] * b2v.x;
                acc[1] += pe[e] * b2v.y;
                acc[2] += pe[e] * b2v.z;
                acc[3] += pe[e] * b2v.w;
            }
            *(f32x4*)(out + (size_t)tok * H + h0) = acc;
        }
    }
}

extern "C" void kernel_launch(void* const* d_in, const int* in_sizes, int n_in,
                              void* d_out, int out_size, void* d_ws, size_t ws_size,
                              hipStream_t stream) {
    const float* x  = (const float*)d_in[0];
    const float* Wg = (const float*)d_in[1];
    const float* bg = (const float*)d_in[2];
    const float* W1 = (const float*)d_in[3];
    const float* b1 = (const float*)d_in[4];
    const float* W2 = (const float*)d_in[5];
    const float* b2 = (const float*)d_in[6];
    float* out = (float*)d_out;

    _Float16* W1p = (_Float16*)d_ws;                       // packed GEMM1 frags, 2 MB
    _Float16* W2p = W1p + (size_t)E * F * H;               // packed GEMM2 frags, 2 MB
    float* probs  = (float*)(W2p + (size_t)64 * 16384);    // [T][E] fp32, 1 MB

    prep_w1p<<<128, 256, 0, stream>>>(W1, W1p);
    prep_w2p<<<256, 256, 0, stream>>>(W2, W2p);
    gate_kernel<<<(T_TOK * E) / 256, 256, 0, stream>>>(x, Wg, bg, probs);
    moe_main<<<T_TOK / BM, 512, 0, stream>>>(x, W1p, b1, W2p, b2, probs, out);
}